// Round 2
// baseline (1298.971 us; speedup 1.0000x reference)
//
#include <hip/hip_runtime.h>
#include <math.h>

// ---------------------------------------------------------------------------
// Mlp_moe: fused shared-MLP over all 582 tokens (patch out + e0 for cls rows),
// small MoE path for cls tokens, top-2 gating, in-place mix into d_out.
// Big GEMMs: 256x256 tile, BK=64, 8 waves, 8-phase counted-vmcnt schedule
// (T2 swizzle + T3/T4 counted pipeline + T5 setprio). bf16 MFMA 16x16x32.
// ---------------------------------------------------------------------------

typedef unsigned short bfu;                                   // bf16 bits
typedef __attribute__((ext_vector_type(8))) short bf16x8;     // MFMA A/B frag
typedef __attribute__((ext_vector_type(4))) float f32x4;      // MFMA C/D frag

#define GLD_LDS16(g, l)                                                        \
  __builtin_amdgcn_global_load_lds(                                            \
      (const __attribute__((address_space(1))) void*)(g),                      \
      (__attribute__((address_space(3))) void*)(l), 16, 0, 0)

#define BAR() asm volatile("s_barrier" ::: "memory")
#define VMW(n) asm volatile("s_waitcnt vmcnt(" #n ")" ::: "memory")

__device__ __forceinline__ bfu f2bf(float f) {
  unsigned int u = __float_as_uint(f);
  u += 0x7FFFu + ((u >> 16) & 1u);  // RNE
  return (bfu)(u >> 16);
}
__device__ __forceinline__ float gelu_exact(float v) {
  return 0.5f * v * (1.0f + erff(v * 0.70710678118654752440f));
}

// ---------------------------------------------------------------------------
// 256x256 8-phase GEMM:  C[256 x 256] = A[256 x K] * Bt[256 x K]^T (+bias[,gelu])
// A row-major (lda=K), Bt row-major NxK (ldb=K).
// LDS: 8 planes of 16KB: [buf(2)][mat A/B(2)][kk(2)] x (256 rows x 32 bf16).
// Swizzle: slot' = slot ^ ((row>>1)&3)  (both-sides: pre-swizzled source).
// Stage stream: planes in order (A0,B0,A1,B1) per K-tile, 1 plane per phase,
// into buf[(tile)&1]; counted vmcnt(8) twice per tile (4-phase slack).
// ---------------------------------------------------------------------------
template <bool GELU, bool OUTBF>
__global__ __launch_bounds__(512, 2) void gemm256_kernel(
    const bfu* __restrict__ A, const bfu* __restrict__ Bt,
    const float* __restrict__ bias, void* __restrict__ out, int K, int ldo,
    int mrows) {
  __shared__ bfu lds[8 * 8192];  // 128 KiB

  const int tid = threadIdx.x;
  const int lane = tid & 63;
  const int wv = tid >> 6;   // 0..7
  const int wm2 = wv >> 2;   // 0..1  (row half)
  const int wn4 = wv & 3;    // 0..3  (col quarter)
  const int lrow = lane & 15;
  const int lks = lane >> 4;

  // XCD-bijective block swizzle (m204)
  int nwg = gridDim.x * gridDim.y;
  int orig = blockIdx.y * gridDim.x + blockIdx.x;
  int q = nwg >> 3, r = nwg & 7;
  int xcd = orig & 7, loc = orig >> 3;
  int w = (xcd < r) ? (xcd * (q + 1) + loc) : (r * (q + 1) + (xcd - r) * q + loc);
  int bx = w % gridDim.x, by = w / gridDim.x;

  const size_t m0 = (size_t)bx * 256;
  const size_t n0 = (size_t)by * 256;
  const bfu* Atile = A + m0 * K;
  const bfu* Btile = Bt + n0 * K;

  const int NT = K >> 6;        // number of 64-wide K tiles (>= 2)
  const int NPLANES = NT * 4;

  int nextplane = 0;
  auto STAGE = [&]() {
    if (nextplane >= NPLANES) return;
    int pidx = nextplane++;
    int t = pidx >> 2, pl = pidx & 3;   // pl: 0=A,kk0 1=B,kk0 2=A,kk1 3=B,kk1
    int mat = pl & 1, kk = pl >> 1;
    int buf = t & 1;
    const bfu* src = mat ? Btile : Atile;
    bfu* base = lds + (((((buf << 1) | mat) << 1) | kk) * 8192);
    int kbase = t * 64 + kk * 32;
#pragma unroll
    for (int i = 0; i < 2; ++i) {
      int idx = i * 512 + tid;
      int row = idx >> 2, slot = idx & 3;
      int gslot = slot ^ ((row >> 1) & 3);  // pre-swizzled source (involution)
      GLD_LDS16(src + (size_t)row * K + kbase + gslot * 8,
                base + i * 4096 + wv * 512);
    }
  };

  const f32x4 fz = {0.f, 0.f, 0.f, 0.f};
  f32x4 acc[8][4];
#pragma unroll
  for (int m = 0; m < 8; ++m)
#pragma unroll
    for (int n = 0; n < 4; ++n) acc[m][n] = fz;

  // prologue: 6 planes in flight (tile0 full + tile1 A0,B0)
  for (int i = 0; i < 6; ++i) STAGE();
  VMW(8);  // tile0 A0,B0 landed (own loads; every wave does likewise)
  BAR();

  bf16x8 bfrag[4];
  for (int t = 0; t < NT; ++t) {
    const int buf = t & 1;
#pragma unroll
    for (int kk = 0; kk < 2; ++kk) {
      const bfu* Ap = lds + (((((buf << 1) | 0) << 1) | kk) * 8192);
      const bfu* Bp = lds + (((((buf << 1) | 1) << 1) | kk) * 8192);
#pragma unroll
      for (int h = 0; h < 2; ++h) {
        // ---- read region: ds_read subtile + issue 1 plane stage ----
        bf16x8 af[4];
        if (h == 0) {
#pragma unroll
          for (int n = 0; n < 4; ++n) {
            int row = wn4 * 64 + n * 16 + lrow;
            bfrag[n] =
                *(const bf16x8*)(Bp + row * 32 + (lks ^ ((row >> 1) & 3)) * 8);
          }
        }
#pragma unroll
        for (int m = 0; m < 4; ++m) {
          int row = wm2 * 128 + (h * 4 + m) * 16 + lrow;
          af[m] =
              *(const bf16x8*)(Ap + row * 32 + (lks ^ ((row >> 1) & 3)) * 8);
        }
        STAGE();
        BAR();
        // ---- MFMA region (compiler inserts lgkmcnt for af/bfrag deps) ----
        __builtin_amdgcn_s_setprio(1);
#pragma unroll
        for (int m = 0; m < 4; ++m)
#pragma unroll
          for (int n = 0; n < 4; ++n)
            acc[h * 4 + m][n] = __builtin_amdgcn_mfma_f32_16x16x32_bf16(
                af[m], bfrag[n], acc[h * 4 + m][n], 0, 0, 0);
        __builtin_amdgcn_s_setprio(0);
        // ---- counted waits guarding the next plane-pair's reads ----
        if (h == 1) {
          if (kk == 0) {
            if (t < NT - 1) {
              VMW(8);   // A1,B1 of tile t landed
            } else {
              VMW(0);   // last tile: everything landed
            }
          } else {
            if (t < NT - 2) {
              VMW(8);   // A0,B0 of tile t+1 landed
            } else if (t == NT - 2) {
              VMW(4);   // stream exhausted: only 2 planes still in flight
            }
          }
        }
        BAR();
      }
    }
  }

  // epilogue: D mapping col=lane&15, row=(lane>>4)*4+r
  const int rbase = lks * 4;
#pragma unroll
  for (int n = 0; n < 4; ++n) {
    int col = wn4 * 64 + n * 16 + lrow;
    float bv = bias[n0 + col];
#pragma unroll
    for (int m = 0; m < 8; ++m) {
#pragma unroll
      for (int rr = 0; rr < 4; ++rr) {
        int row = wm2 * 128 + m * 16 + rbase + rr;
        if ((int)(m0 + row) < mrows) {
          float v = acc[m][n][rr] + bv;
          if (GELU) v = gelu_exact(v);
          size_t o = (m0 + row) * (size_t)ldo + (n0 + col);
          if (OUTBF)
            ((bfu*)out)[o] = f2bf(v);
          else
            ((float*)out)[o] = v;
        }
      }
    }
  }
}

// ---------------------------------------------------------------------------
// Small 2-phase MFMA tile for the MoE cls path (unchanged, proven correct).
// ---------------------------------------------------------------------------
template <int BM, int WC, int MF, int NF, bool GELU, bool OUTBF>
__device__ __forceinline__ void gemm_tile(
    bfu* As, bfu* Bs, const bfu* __restrict__ A, const bfu* __restrict__ Bt,
    const float* __restrict__ bias, void* __restrict__ out, int K, int ldo) {
  const int tid = threadIdx.x;
  const int lane = tid & 63;
  const int wv = tid >> 6;
  const int wm = (wv / WC) * (MF * 16);
  const int wn = (wv % WC) * (NF * 16);

  const f32x4 fzero = {0.f, 0.f, 0.f, 0.f};
  f32x4 acc[MF][NF];
#pragma unroll
  for (int m = 0; m < MF; ++m)
#pragma unroll
    for (int n = 0; n < NF; ++n) acc[m][n] = fzero;

  const int srow = tid >> 3;
  const int gslot = (tid & 7) ^ (srow & 7);
  const bfu* ga = A + (size_t)srow * K + gslot * 8;
  const bfu* gb = Bt + (size_t)srow * K + gslot * 8;

  const int lrow = lane & 15;
  const int lks = lane >> 4;

  for (int kt = 0; kt < K; kt += 64) {
#pragma unroll
    for (int i = 0; i < BM / 32; ++i)
      GLD_LDS16(ga + kt + (size_t)i * 32 * K, As + i * 2048 + wv * 512);
#pragma unroll
    for (int i = 0; i < 4; ++i)
      GLD_LDS16(gb + kt + (size_t)i * 32 * K, Bs + i * 2048 + wv * 512);
    __syncthreads();

#pragma unroll
    for (int kk = 0; kk < 2; ++kk) {
      bf16x8 af[MF], bfr[NF];
#pragma unroll
      for (int m = 0; m < MF; ++m) {
        int row = wm + m * 16 + lrow;
        int slot = (kk * 4 + lks) ^ (row & 7);
        af[m] = *(const bf16x8*)(As + row * 64 + slot * 8);
      }
#pragma unroll
      for (int n = 0; n < NF; ++n) {
        int row = wn + n * 16 + lrow;
        int slot = (kk * 4 + lks) ^ (row & 7);
        bfr[n] = *(const bf16x8*)(Bs + row * 64 + slot * 8);
      }
#pragma unroll
      for (int m = 0; m < MF; ++m)
#pragma unroll
        for (int n = 0; n < NF; ++n)
          acc[m][n] = __builtin_amdgcn_mfma_f32_16x16x32_bf16(af[m], bfr[n],
                                                              acc[m][n], 0, 0, 0);
    }
    __syncthreads();
  }

  const int rbase = (lane >> 4) * 4;
#pragma unroll
  for (int n = 0; n < NF; ++n) {
    int col = wn + n * 16 + lrow;
    float bv = bias[col];
#pragma unroll
    for (int m = 0; m < MF; ++m) {
#pragma unroll
      for (int r = 0; r < 4; ++r) {
        int row = wm + m * 16 + rbase + r;
        float v = acc[m][n][r] + bv;
        if (GELU) v = gelu_exact(v);
        if (OUTBF)
          ((bfu*)out)[(size_t)row * ldo + col] = f2bf(v);
        else
          ((float*)out)[(size_t)row * ldo + col] = v;
      }
    }
  }
}

// hid_t = gelu(cls_t @ W_in[t%5] + b_in[t%5])  -> bf16 [6][64][3072]
__global__ __launch_bounds__(256) void hidc_kernel(
    const bfu* __restrict__ clsb, const bfu* __restrict__ WinT,
    const float* __restrict__ b_in, bfu* __restrict__ hidc) {
  __shared__ bfu As[64 * 64];
  __shared__ bfu Bs[128 * 64];
  int t = blockIdx.y, a = t % 5, nt = blockIdx.x;
  gemm_tile<64, 4, 4, 2, true, true>(
      As, Bs, clsb + (size_t)t * 64 * 768,
      WinT + (size_t)a * 3072 * 768 + (size_t)nt * 128 * 768,
      b_in + a * 3072 + nt * 128,
      (void*)(hidc + (size_t)t * 64 * 3072 + nt * 128), 768, 3072);
}

// allo_t = hid_t @ [W_out^T concat over o] + b_out  -> f32 [6][64][3840]
__global__ __launch_bounds__(256) void allo_kernel(
    const bfu* __restrict__ hidc, const bfu* __restrict__ WoutT,
    const float* __restrict__ b_out, float* __restrict__ allo) {
  __shared__ bfu As[64 * 64];
  __shared__ bfu Bs[128 * 64];
  int t = blockIdx.y, nt = blockIdx.x;
  gemm_tile<64, 4, 4, 2, false, false>(
      As, Bs, hidc + (size_t)t * 64 * 3072,
      WoutT + (size_t)nt * 128 * 3072, b_out + nt * 128,
      (void*)(allo + (size_t)t * 64 * 3840 + nt * 128), 3072, 3840);
}

// -------------------- conversion / layout kernels --------------------
__global__ __launch_bounds__(256) void cvt_f32_bf16_kernel(
    const float* __restrict__ in, bfu* __restrict__ out, int n4) {
  int stride = gridDim.x * blockDim.x;
  for (int i = blockIdx.x * blockDim.x + threadIdx.x; i < n4; i += stride) {
    float4 v = ((const float4*)in)[i];
    ushort4 o;
    o.x = f2bf(v.x); o.y = f2bf(v.y); o.z = f2bf(v.z); o.w = f2bf(v.w);
    ((ushort4*)out)[i] = o;
  }
}

// z==0: s0/d0 ; z>0: s1/d1 plane (z-1).  f32 [R][C] -> bf16 [C][R]
__global__ __launch_bounds__(256) void transpose2_kernel(
    const float* __restrict__ s0, const float* __restrict__ s1,
    bfu* __restrict__ d0, bfu* __restrict__ d1, int R, int C) {
  __shared__ float tile[32][33];
  int z = blockIdx.z;
  const float* src = (z == 0) ? s0 : s1 + (size_t)(z - 1) * R * C;
  bfu* dst = (z == 0) ? d0 : d1 + (size_t)(z - 1) * R * C;
  int c0 = blockIdx.x * 32, r0 = blockIdx.y * 32;
  int tx = threadIdx.x, ty = threadIdx.y;  // 32 x 8
#pragma unroll
  for (int j = 0; j < 32; j += 8)
    tile[ty + j][tx] = src[(size_t)(r0 + ty + j) * C + c0 + tx];
  __syncthreads();
#pragma unroll
  for (int j = 0; j < 32; j += 8)
    dst[(size_t)(c0 + ty + j) * R + r0 + tx] = f2bf(tile[tx][ty + j]);
}

// clsb[t][b][d] = bf16(x[b][t][d])
__global__ __launch_bounds__(256) void build_clsb_kernel(
    const float* __restrict__ x, bfu* __restrict__ clsb) {
  int i = blockIdx.x * 256 + threadIdx.x;
  int d = i % 768, bt = i / 768;
  int b = bt % 64, t = bt / 64;
  clsb[i] = f2bf(x[((size_t)b * 582 + t) * 768 + d]);
}

// top-2 renormalized softmax gate weights gw[b*6+t][0..5]
__global__ __launch_bounds__(64) void gate_kernel(
    const float* __restrict__ x, const float* __restrict__ Wg,
    float* __restrict__ gw) {
  int bt = blockIdx.x;
  int b = bt / 6, t = bt % 6;
  const float* xr = x + ((size_t)b * 582 + t) * 768;
  const float* wg = Wg + (size_t)t * 768 * 6;
  int lane = threadIdx.x;
  float z[6] = {0.f, 0.f, 0.f, 0.f, 0.f, 0.f};
  for (int d = lane; d < 768; d += 64) {
    float xv = xr[d];
#pragma unroll
    for (int o = 0; o < 6; ++o) z[o] += xv * wg[d * 6 + o];
  }
#pragma unroll
  for (int o = 0; o < 6; ++o)
#pragma unroll
    for (int s = 32; s > 0; s >>= 1) z[o] += __shfl_down(z[o], s);
  if (lane == 0) {
    int i1 = 0;
#pragma unroll
    for (int o = 1; o < 6; ++o) if (z[o] > z[i1]) i1 = o;
    int i2 = -1;
#pragma unroll
    for (int o = 0; o < 6; ++o) {
      if (o == i1) continue;
      if (i2 < 0 || z[o] > z[i2]) i2 = o;
    }
    float w1 = 1.f / (1.f + expf(z[i2] - z[i1]));
    float o6[6] = {0.f, 0.f, 0.f, 0.f, 0.f, 0.f};
    o6[i1] = w1; o6[i2] = 1.f - w1;
#pragma unroll
    for (int o = 0; o < 6; ++o) gw[bt * 6 + o] = o6[o];
  }
}

// cls rows of d_out currently hold e0; replace with gated mixture
__global__ __launch_bounds__(256) void mix_kernel(
    float* __restrict__ out, const float* __restrict__ allo,
    const float* __restrict__ gw) {
  int bt = blockIdx.x;
  int b = bt / 6, t = bt % 6;
  float g[6];
#pragma unroll
  for (int o = 0; o < 6; ++o) g[o] = gw[bt * 6 + o];
  float* orow = out + ((size_t)b * 582 + t) * 768;
  const float* arow = allo + ((size_t)t * 64 + b) * 3840;
  for (int d = threadIdx.x; d < 768; d += 256) {
    float v = g[0] * orow[d];
#pragma unroll
    for (int o = 0; o < 5; ++o) v += g[o + 1] * arow[o * 768 + d];
    orow[d] = v;
  }
}

// ---------------------------------------------------------------------------
extern "C" void kernel_launch(void* const* d_in, const int* in_sizes, int n_in,
                              void* d_out, int out_size, void* d_ws,
                              size_t ws_size, hipStream_t stream) {
  const float* x = (const float*)d_in[0];
  const float* W1 = (const float*)d_in[1];
  const float* b1 = (const float*)d_in[2];
  const float* W2 = (const float*)d_in[3];
  const float* b2 = (const float*)d_in[4];
  const float* W_in = (const float*)d_in[5];
  const float* b_in = (const float*)d_in[6];
  const float* W_out = (const float*)d_in[7];
  const float* b_out = (const float*)d_in[8];
  const float* Wg = (const float*)d_in[9];
  float* out = (float*)d_out;

  constexpr int M = 37248;  // 64*582
  constexpr size_t SZ_XB = (size_t)M * 768 * 2;
  constexpr size_t SZ_W1T = (size_t)3072 * 768 * 2;
  constexpr size_t SZ_W2T = (size_t)768 * 3072 * 2;
  constexpr size_t SZ_WINT = (size_t)5 * 3072 * 768 * 2;
  constexpr size_t SZ_WOUTT = (size_t)5 * 768 * 3072 * 2;
  constexpr size_t SZ_HID = (size_t)12544 * 3072 * 2;
  constexpr size_t SZ_CLSB = (size_t)6 * 64 * 768 * 2;
  constexpr size_t SZ_HIDC = (size_t)6 * 64 * 3072 * 2;
  constexpr size_t SZ_ALLO = (size_t)6 * 64 * 3840 * 4;
  constexpr size_t SZ_GW = (size_t)384 * 6 * 4;

  char* ws = (char*)d_ws;
  size_t off = 0;
  auto take = [&](size_t bytes) {
    char* p = ws + off;
    off += (bytes + 255) & ~(size_t)255;
    return p;
  };
  bfu* xb = (bfu*)take(SZ_XB);
  bfu* W1t = (bfu*)take(SZ_W1T);
  bfu* W2t = (bfu*)take(SZ_W2T);
  bfu* WinT = (bfu*)take(SZ_WINT);
  bfu* WoutT = (bfu*)take(SZ_WOUTT);
  bfu* hid = (bfu*)take(SZ_HID);
  bfu* clsb = (bfu*)take(SZ_CLSB);
  bfu* hidc = (bfu*)take(SZ_HIDC);
  float* allo = (float*)take(SZ_ALLO);
  float* gw = (float*)take(SZ_GW);
  if (ws_size < off) return;

  // --- layout/conversion passes ---
  cvt_f32_bf16_kernel<<<2048, 256, 0, stream>>>(x, xb, M * 768 / 4);
  transpose2_kernel<<<dim3(96, 24, 6), dim3(32, 8), 0, stream>>>(
      W1, W_in, W1t, WinT, 768, 3072);
  transpose2_kernel<<<dim3(24, 96, 6), dim3(32, 8), 0, stream>>>(
      W2, W_out, W2t, WoutT, 3072, 768);
  build_clsb_kernel<<<(6 * 64 * 768) / 256, 256, 0, stream>>>(x, clsb);
  gate_kernel<<<384, 64, 0, stream>>>(x, Wg, gw);

  // --- big shared MLP over all tokens (patch output + e0 for cls rows) ---
  // chunks padded to 256-divisible tile counts; store-side row guards
  const int cstart[4] = {0, 12544, 25088, 37376};
  for (int c = 0; c < 3; ++c) {
    int start = cstart[c];
    int alloc = cstart[c + 1] - start;  // 12544,12544,12288
    int mtiles = alloc / 256;           // 49,49,48
    int valid = M - start < alloc ? M - start : alloc;  // 12544,12544,12160
    gemm256_kernel<true, true><<<dim3(mtiles, 12), 512, 0, stream>>>(
        xb + (size_t)start * 768, W1t, b1, (void*)hid, 768, 3072, valid);
    gemm256_kernel<false, false><<<dim3(mtiles, 3), 512, 0, stream>>>(
        hid, W2t, b2, (void*)(out + (size_t)start * 768), 3072, 768, valid);
  }

  // --- MoE cls path ---
  hidc_kernel<<<dim3(24, 6), 256, 0, stream>>>(clsb, WinT, b_in, hidc);
  allo_kernel<<<dim3(30, 6), 256, 0, stream>>>(hidc, WoutT, b_out, allo);
  mix_kernel<<<384, 256, 0, stream>>>(out, allo, gw);
}